// Round 1
// baseline (1534.339 us; speedup 1.0000x reference)
//
#include <hip/hip_runtime.h>
#include <math.h>

#define N_NODES 50000
#define N_EDGES 500000

__device__ __forceinline__ float gelu_tanh(float x) {
    const float k0 = 0.7978845608028654f;
    const float k1 = 0.044715f;
    float inner = k0 * (x + k1 * x * x * x);
    return 0.5f * x * (1.0f + tanhf(inner));
}

// K1: per-node lift. feat_s (N,32), feat_v (N,32,3) -> ws ; a*self -> d_out (all 128)
__global__ void node_pre(const float* __restrict__ node_input,
                         const float* __restrict__ W1_s,
                         const float* __restrict__ W1_v,
                         float* __restrict__ feat_s,
                         float* __restrict__ feat_v,
                         float* __restrict__ out) {
    __shared__ float lWs[32 * 64];
    __shared__ float lWv[32 * 64];
    for (int i = threadIdx.x; i < 2048; i += blockDim.x) {
        lWs[i] = W1_s[i];
        lWv[i] = W1_v[i];
    }
    __syncthreads();
    int n = blockIdx.x * blockDim.x + threadIdx.x;
    if (n >= N_NODES) return;
    const float inv_sqrt_mul = 0.17677669529663687f;  // 1/sqrt(32)
    const float a_mix = 0.9219544457292887f;          // sqrt(0.85)

    float s[32];
#pragma unroll
    for (int u = 0; u < 32; ++u) s[u] = node_input[n * 128 + u];
#pragma unroll 4
    for (int w = 0; w < 64; ++w) {
        float acc = 0.f;
#pragma unroll
        for (int u = 0; u < 32; ++u) acc += s[u] * lWs[u * 64 + w];
        acc *= inv_sqrt_mul;
        if (w < 32) feat_s[n * 32 + w] = acc;
        else        out[n * 128 + (w - 32)] = a_mix * acc;
    }
#pragma unroll
    for (int k = 0; k < 3; ++k) {
        float vk[32];
#pragma unroll
        for (int u = 0; u < 32; ++u) vk[u] = node_input[n * 128 + 32 + u * 3 + k];
#pragma unroll 4
        for (int w = 0; w < 64; ++w) {
            float acc = 0.f;
#pragma unroll
            for (int u = 0; u < 32; ++u) acc += vk[u] * lWv[u * 64 + w];
            acc *= inv_sqrt_mul;
            if (w < 32) feat_v[n * 96 + w * 3 + k] = acc;
            else        out[n * 128 + 32 + (w - 32) * 3 + k] = a_mix * acc;
        }
    }
}

// K2: per-edge. One 32-lane group per edge; lane = u (channel).
__global__ void edge_kernel(const float* __restrict__ edge_attr,
                            const float* __restrict__ edge_scalars,
                            const int* __restrict__ edge_src,
                            const int* __restrict__ edge_dst,
                            const float* __restrict__ M0,
                            const float* __restrict__ M1,
                            const float* __restrict__ Wtp0,
                            const float* __restrict__ Wtp1,
                            const float* __restrict__ Wtp2,
                            const float* __restrict__ Wtp3,
                            const float* __restrict__ feat_s,
                            const float* __restrict__ feat_v,
                            float* __restrict__ acc0,
                            float* __restrict__ acc1,
                            int n_groups) {
    __shared__ float lM0[8 * 32];
    __shared__ float lM1[32 * 32];
    __shared__ float lW0[32 * 32];
    __shared__ float lW1[32 * 32];
    __shared__ float lW2[32 * 32];
    __shared__ float lW3[32 * 32];
    for (int i = threadIdx.x; i < 256; i += blockDim.x) lM0[i] = M0[i];
    for (int i = threadIdx.x; i < 1024; i += blockDim.x) {
        lM1[i] = M1[i];
        lW0[i] = Wtp0[i];
        lW1[i] = Wtp1[i];
        lW2[i] = Wtp2[i];
        lW3[i] = Wtp3[i];
    }
    __syncthreads();
    const int lane = threadIdx.x & 31;  // u channel
    const int group = (blockIdx.x * blockDim.x + threadIdx.x) >> 5;
    const float inv_sqrt8  = 0.35355339059327373f;
    const float inv_sqrt32 = 0.17677669529663687f;
    const float INV3 = 0.5773502691896258f;  // 1/sqrt(3)

    for (int e = group; e < N_EDGES; e += n_groups) {
        const int src = edge_src[e];
        const int dst = edge_dst[e];
        const float y0  = edge_attr[e * 4 + 0];
        const float y1x = edge_attr[e * 4 + 1];
        const float y1y = edge_attr[e * 4 + 2];
        const float y1z = edge_attr[e * 4 + 3];

        // t_u = gelu((x @ M0)/sqrt(8))
        float t = 0.f;
#pragma unroll
        for (int i = 0; i < 8; ++i) t += edge_scalars[e * 8 + i] * lM0[i * 32 + lane];
        t = gelu_tanh(t * inv_sqrt8);
        // h_u = gelu((t @ M1)/sqrt(32))
        float h = 0.f;
#pragma unroll
        for (int m = 0; m < 32; ++m) h += __shfl(t, m, 32) * lM1[m * 32 + lane];
        h = gelu_tanh(h * inv_sqrt32);
        // w* = h @ Wtp* / sqrt(32)
        float w0 = 0.f, w1 = 0.f, w2 = 0.f, w3 = 0.f;
#pragma unroll
        for (int j = 0; j < 32; ++j) {
            float hj = __shfl(h, j, 32);
            w0 += hj * lW0[j * 32 + lane];
            w1 += hj * lW1[j * 32 + lane];
            w2 += hj * lW2[j * 32 + lane];
            w3 += hj * lW3[j * 32 + lane];
        }
        w0 *= inv_sqrt32; w1 *= inv_sqrt32; w2 *= inv_sqrt32; w3 *= inv_sqrt32;

        const float es  = feat_s[src * 32 + lane];
        const float evx = feat_v[src * 96 + lane * 3 + 0];
        const float evy = feat_v[src * 96 + lane * 3 + 1];
        const float evz = feat_v[src * 96 + lane * 3 + 2];
        const float dvy = evx * y1x + evy * y1y + evz * y1z;

        const float out0a = w0 * es * y0;
        const float out0b = w3 * dvy * INV3;
        const float w1es = w1 * es;
        const float w2y0 = w2 * y0;

        float* a0 = acc0 + (size_t)dst * 64;
        float* a1 = acc1 + (size_t)dst * 192;
        unsafeAtomicAdd(a0 + lane,      out0a);
        unsafeAtomicAdd(a0 + 32 + lane, out0b);
        unsafeAtomicAdd(a1 + lane * 3 + 0, w1es * y1x);
        unsafeAtomicAdd(a1 + lane * 3 + 1, w1es * y1y);
        unsafeAtomicAdd(a1 + lane * 3 + 2, w1es * y1z);
        unsafeAtomicAdd(a1 + 96 + lane * 3 + 0, w2y0 * evx);
        unsafeAtomicAdd(a1 + 96 + lane * 3 + 1, w2y0 * evy);
        unsafeAtomicAdd(a1 + 96 + lane * 3 + 2, w2y0 * evz);
    }
}

// K3: per-node projection + mix.  out += b * (acc @ W2) * inv_deg / sqrt(64)
__global__ void node_post(const float* __restrict__ acc0,
                          const float* __restrict__ acc1,
                          const float* __restrict__ W2_s,
                          const float* __restrict__ W2_v,
                          float* __restrict__ out) {
    __shared__ float lWs[64 * 32];
    __shared__ float lWv[64 * 32];
    for (int i = threadIdx.x; i < 2048; i += blockDim.x) {
        lWs[i] = W2_s[i];
        lWv[i] = W2_v[i];
    }
    __syncthreads();
    int n = blockIdx.x * blockDim.x + threadIdx.x;
    if (n >= N_NODES) return;
    // inv_deg * inv_sqrt(64) * b
    const float scale = 0.31622776601683794f * 0.125f * 0.3872983346207417f;

    float ns[64];
#pragma unroll
    for (int j = 0; j < 64; ++j) ns[j] = acc0[(size_t)n * 64 + j];
#pragma unroll 4
    for (int c = 0; c < 32; ++c) {
        float acc = 0.f;
#pragma unroll
        for (int j = 0; j < 64; ++j) acc += ns[j] * lWs[j * 32 + c];
        out[n * 128 + c] += scale * acc;
    }
#pragma unroll
    for (int k = 0; k < 3; ++k) {
        float nvk[64];
#pragma unroll
        for (int j = 0; j < 64; ++j) nvk[j] = acc1[(size_t)n * 192 + j * 3 + k];
#pragma unroll 4
        for (int c = 0; c < 32; ++c) {
            float acc = 0.f;
#pragma unroll
            for (int j = 0; j < 64; ++j) acc += nvk[j] * lWv[j * 32 + c];
            out[n * 128 + 32 + c * 3 + k] += scale * acc;
        }
    }
}

extern "C" void kernel_launch(void* const* d_in, const int* in_sizes, int n_in,
                              void* d_out, int out_size, void* d_ws, size_t ws_size,
                              hipStream_t stream) {
    const float* node_input   = (const float*)d_in[0];
    const float* edge_attr    = (const float*)d_in[1];
    const float* edge_scalars = (const float*)d_in[2];
    const float* W1_s = (const float*)d_in[3];
    const float* W1_v = (const float*)d_in[4];
    const float* M0   = (const float*)d_in[5];
    const float* M1   = (const float*)d_in[6];
    const float* Wtp0 = (const float*)d_in[7];
    const float* Wtp1 = (const float*)d_in[8];
    const float* Wtp2 = (const float*)d_in[9];
    const float* Wtp3 = (const float*)d_in[10];
    const float* W2_s = (const float*)d_in[11];
    const float* W2_v = (const float*)d_in[12];
    const int* edge_src = (const int*)d_in[13];
    const int* edge_dst = (const int*)d_in[14];
    float* out = (float*)d_out;
    float* ws  = (float*)d_ws;

    float* feat_s = ws;                          // N*32
    float* feat_v = ws + (size_t)N_NODES * 32;   // N*96
    float* acc0   = ws + (size_t)N_NODES * 128;  // N*64
    float* acc1   = ws + (size_t)N_NODES * 192;  // N*192
    // total ws use: N*384 floats = 76.8 MB

    hipMemsetAsync(acc0, 0, (size_t)N_NODES * 256 * sizeof(float), stream);

    node_pre<<<(N_NODES + 255) / 256, 256, 0, stream>>>(node_input, W1_s, W1_v,
                                                        feat_s, feat_v, out);

    const int blocks = 2048;
    const int n_groups = blocks * 256 / 32;
    edge_kernel<<<blocks, 256, 0, stream>>>(edge_attr, edge_scalars, edge_src, edge_dst,
                                            M0, M1, Wtp0, Wtp1, Wtp2, Wtp3,
                                            feat_s, feat_v, acc0, acc1, n_groups);

    node_post<<<(N_NODES + 255) / 256, 256, 0, stream>>>(acc0, acc1, W2_s, W2_v, out);
}